// Round 4
// baseline (333.347 us; speedup 1.0000x reference)
//
#include <hip/hip_runtime.h>
#include <hip/hip_fp16.h>
#include <stdint.h>

// Model: v = max_w relu(x @ conv_w^T + conv_b); feat=[v1-v2, v1*v2];
//        out = tanh(feat@fc1^T + b1) @ fc2^T + b2
// B=512, W=128, K=337, OC=300 (pad 320)

#define OC   300
#define OCP  320
#define KD   337
#define NBAT 512
#define NWRD 128
#define NKT  11        // ceil(337/32)
#define XSTR 36        // f32 LDS row stride (dwords): 128*36 = 4608 = 9*512 exactly
#define XDW  (NWRD * XSTR)
#define BGR  1280      // B granules (16B) per k-slice = 320 cols * 4

typedef _Float16 f16x8 __attribute__((ext_vector_type(8)));
typedef float    f32x4 __attribute__((ext_vector_type(4)));

// async global->LDS DMA (size must be a literal at each call site)
#define GL_LDS(gp, lp, SZ)                                                        \
  __builtin_amdgcn_global_load_lds(                                               \
      (const __attribute__((address_space(1))) uint32_t*)(gp),                    \
      (__attribute__((address_space(3))) uint32_t*)(lp), SZ, 0, 0)

// Weights pre-swizzled so the LINEAR LDS DMA image is fragment-conflict-free:
// granule (o,g) of k-slice kt lives at flat slot kt*1280 + ((o*4+g) ^ (o&7)).
__global__ void prep_w_kernel(const float* __restrict__ cw, __half* __restrict__ Wp) {
  int i = blockIdx.x * 256 + threadIdx.x;
  if (i >= NKT * BGR) return;
  int kt = i / BGR, lin = i - kt * BGR;
  int o = lin >> 2, g = lin & 3;
  int slot = lin ^ (o & 7);
  __half h[8];
  #pragma unroll
  for (int e = 0; e < 8; ++e) {
    int k = kt * 32 + g * 8 + e;
    float v = (o < OC && k < KD) ? cw[o * KD + k] : 0.f;   // zero pad (kills A-garbage)
    h[e] = __float2half(v);
  }
  *reinterpret_cast<uint4*>(Wp + (size_t)(kt * BGR + slot) * 8) =
      *reinterpret_cast<const uint4*>(h);
}

__global__ void prep_fc1t_kernel(const float* __restrict__ w, float* __restrict__ T) {
  int i = blockIdx.x * 256 + threadIdx.x;
  if (i >= 300 * 600) return;
  int j = i / 600, k = i - j * 600;
  T[k * 300 + j] = w[i];
}

// 1024 blocks (1 item each), 512 thr = 8 waves (2M x 4N), 2 blocks/CU resident.
// Per kt: DMA-prefetch tile kt+1 (x f32 + pre-swizzled B f16) into the other
// buffer, ds_read fragments of kt, cvt A to f16, 20 MFMA, one barrier.
__global__ __launch_bounds__(512, 4) void encode_gemm(
    const float* __restrict__ x1, const float* __restrict__ x2,
    const __half* __restrict__ Wp, const float* __restrict__ cb,
    float* __restrict__ V)
{
  __shared__ float Xt[2][XDW];       // 36,864 B
  __shared__ uint4 Bt[2][BGR];       // 40,960 B
  __shared__ float colmax[2][OCP];   //  2,560 B   (total 80,384 -> 2 blocks/CU)

  const int tid  = threadIdx.x;
  const int lane = tid & 63;
  const int wid  = tid >> 6;
  const int wm   = wid >> 2;
  const int wn   = wid & 3;
  const int ib   = blockIdx.x;
  const float* xb = (ib < NBAT ? x1 : x2) + (size_t)(ib & (NBAT - 1)) * (NWRD * KD);

  // decode the 9 LDS slots this thread fills: slot s = j*512+tid -> (row, col)
  int rk[9];
  #pragma unroll
  for (int j = 0; j < 9; ++j) {
    int s = j * 512 + tid;
    int r = s / XSTR, k = s - r * XSTR;
    rk[j] = (r << 8) | ((k < 32) ? k : 31);    // pad cols clamp to col 31 (same line)
  }

  #define ISSUE(KT, BUF) do {                                                        \
    const int kt_ = (KT);                                                            \
    const int ko_ = kt_ * 32;                                                        \
    _Pragma("unroll")                                                                \
    for (int j = 0; j < 9; ++j) {                                                    \
      int r_ = rk[j] >> 8, kc_ = rk[j] & 255;                                        \
      int gk_ = ko_ + kc_; gk_ = (gk_ > KD - 1) ? (KD - 1) : gk_;  /* tail clamp */  \
      GL_LDS(xb + (size_t)r_ * KD + gk_, &Xt[BUF][j * 512 + tid], 4);                \
    }                                                                                \
    const __half* wsrc_ = Wp + (size_t)kt_ * BGR * 8;                                \
    GL_LDS(wsrc_ + (size_t)tid * 8,          &Bt[BUF][tid],        16);              \
    GL_LDS(wsrc_ + (size_t)(tid + 512) * 8,  &Bt[BUF][tid + 512],  16);              \
    if (tid < 256)                                                                   \
      GL_LDS(wsrc_ + (size_t)(tid + 1024) * 8, &Bt[BUF][tid + 1024], 16);            \
  } while (0)

  f32x4 acc[4][5];
  #pragma unroll
  for (int mi = 0; mi < 4; ++mi)
    #pragma unroll
    for (int ni = 0; ni < 5; ++ni)
      acc[mi][ni] = (f32x4){0.f, 0.f, 0.f, 0.f};

  ISSUE(0, 0);
  asm volatile("s_waitcnt vmcnt(0)" ::: "memory");
  __syncthreads();

  const int k0 = (lane >> 4) * 8;
  for (int kt = 0; kt < NKT; ++kt) {
    const int cur = kt & 1;
    if (kt + 1 < NKT) ISSUE(kt + 1, cur ^ 1);

    // A fragments: ds_read f32x8 (stride-36 rows -> bank-uniform), cvt -> f16
    f16x8 a[4];
    #pragma unroll
    for (int mi = 0; mi < 4; ++mi) {
      int r = wm * 64 + mi * 16 + (lane & 15);
      const float* xp = &Xt[cur][r * XSTR + k0];
      f32x4 lo = *reinterpret_cast<const f32x4*>(xp);
      f32x4 hi = *reinterpret_cast<const f32x4*>(xp + 4);
      f16x8 v;
      v[0] = (_Float16)lo[0]; v[1] = (_Float16)lo[1];
      v[2] = (_Float16)lo[2]; v[3] = (_Float16)lo[3];
      v[4] = (_Float16)hi[0]; v[5] = (_Float16)hi[1];
      v[6] = (_Float16)hi[2]; v[7] = (_Float16)hi[3];
      a[mi] = v;
    }
    // B fragments from pre-swizzled image; 20 MFMA
    #pragma unroll
    for (int ni = 0; ni < 5; ++ni) {
      int o    = wn * 80 + ni * 16 + (lane & 15);
      int slot = (o * 4 + (lane >> 4)) ^ (o & 7);
      f16x8 b = *reinterpret_cast<const f16x8*>(&Bt[cur][slot]);
      #pragma unroll
      for (int mi = 0; mi < 4; ++mi)
        acc[mi][ni] = __builtin_amdgcn_mfma_f32_16x16x32_f16(a[mi], b, acc[mi][ni], 0, 0, 0);
    }

    asm volatile("s_waitcnt vmcnt(0)" ::: "memory");  // DMA for kt+1 landed
    __syncthreads();
  }

  // epilogue: max over 128 rows -> relu(max + bias) (relu monotone, bias per-col)
  // C/D layout: col = lane&15, rows spread over (lane>>4, reg)
  #pragma unroll
  for (int ni = 0; ni < 5; ++ni) {
    float m = acc[0][ni][0];
    #pragma unroll
    for (int mi = 0; mi < 4; ++mi)
      #pragma unroll
      for (int j = 0; j < 4; ++j)
        m = fmaxf(m, acc[mi][ni][j]);
    m = fmaxf(m, __shfl_xor(m, 16));
    m = fmaxf(m, __shfl_xor(m, 32));
    if (lane < 16) colmax[wm][wn * 80 + ni * 16 + lane] = m;
  }
  __syncthreads();
  if (tid < OCP) {
    float v = fmaxf(colmax[0][tid], colmax[1][tid]);
    if (tid < OC) V[(size_t)ib * OC + tid] = fmaxf(v + cb[tid], 0.f);
  }
}

// 64 blocks x 320 thr, 8 batch items per block.
__global__ __launch_bounds__(320) void head_kernel(
    const float* __restrict__ V, const float* __restrict__ T,
    const float* __restrict__ fc1b, const float* __restrict__ fc2w,
    const float* __restrict__ fc2b, float* __restrict__ out)
{
  __shared__ float feat[8][600];
  __shared__ float partial[8][5];
  const int tid  = threadIdx.x;
  const int lane = tid & 63;
  const int wid  = tid >> 6;
  const int b0   = blockIdx.x * 8;

  for (int idx = tid; idx < 8 * 600; idx += 320) {
    int q = idx / 600, k = idx - q * 600;
    int b = b0 + q;
    int c = (k < 300) ? k : k - 300;
    float a1 = V[(size_t)b * OC + c];
    float a2 = V[(size_t)(NBAT + b) * OC + c];
    feat[q][k] = (k < 300) ? (a1 - a2) : (a1 * a2);
  }
  __syncthreads();

  const int j = tid;
  float h[8] = {0.f, 0.f, 0.f, 0.f, 0.f, 0.f, 0.f, 0.f};
  if (j < 300) {
    for (int k4 = 0; k4 < 150; ++k4) {
      float w0 = T[(k4 * 4 + 0) * 300 + j];
      float w1 = T[(k4 * 4 + 1) * 300 + j];
      float w2 = T[(k4 * 4 + 2) * 300 + j];
      float w3 = T[(k4 * 4 + 3) * 300 + j];
      #pragma unroll
      for (int q = 0; q < 8; ++q) {
        float4 fv = *reinterpret_cast<const float4*>(&feat[q][k4 * 4]);
        h[q] = fmaf(fv.x, w0, h[q]);
        h[q] = fmaf(fv.y, w1, h[q]);
        h[q] = fmaf(fv.z, w2, h[q]);
        h[q] = fmaf(fv.w, w3, h[q]);
      }
    }
  }
  float bias = (j < 300) ? fc1b[j] : 0.f;
  float w2j  = (j < 300) ? fc2w[j] : 0.f;
  #pragma unroll
  for (int q = 0; q < 8; ++q) {
    float g = (j < 300) ? tanhf(h[q] + bias) * w2j : 0.f;
    #pragma unroll
    for (int s = 1; s < 64; s <<= 1) g += __shfl_xor(g, s);
    if (lane == 0) partial[q][wid] = g;
  }
  __syncthreads();
  if (tid < 8) {
    float s = fc2b[0];
    #pragma unroll
    for (int wv = 0; wv < 5; ++wv) s += partial[tid][wv];
    out[b0 + tid] = s;
  }
}

extern "C" void kernel_launch(void* const* d_in, const int* in_sizes, int n_in,
                              void* d_out, int out_size, void* d_ws, size_t ws_size,
                              hipStream_t stream) {
  const float* x1     = (const float*)d_in[0];
  const float* x2     = (const float*)d_in[1];
  const float* conv_w = (const float*)d_in[2];
  const float* conv_b = (const float*)d_in[3];
  const float* fc1_w  = (const float*)d_in[4];
  const float* fc1_b  = (const float*)d_in[5];
  const float* fc2_w  = (const float*)d_in[6];
  const float* fc2_b  = (const float*)d_in[7];
  float* out = (float*)d_out;

  uint8_t* ws = (uint8_t*)d_ws;
  __half* Wp = (__half*)ws;                                // 11*1280*16 = 225,280 B
  float*  V  = (float*)(ws + 225280);                      // 1024*300*4 = 1,228,800 B
  float*  T  = (float*)(ws + 225280 + 1228800);            // 600*300*4  = 720,000 B

  prep_w_kernel<<<(NKT * BGR + 255) / 256, 256, 0, stream>>>(conv_w, Wp);
  prep_fc1t_kernel<<<(300 * 600 + 255) / 256, 256, 0, stream>>>(fc1_w, T);
  encode_gemm<<<1024, 512, 0, stream>>>(x1, x2, Wp, conv_b, V);
  head_kernel<<<64, 320, 0, stream>>>(V, T, fc1_b, fc2_w, fc2_b, out);
}

// Round 5
// 313.127 us; speedup vs baseline: 1.0646x; 1.0646x over previous
//
#include <hip/hip_runtime.h>
#include <hip/hip_fp16.h>
#include <stdint.h>

// Model: v = max_w relu(x @ conv_w^T + conv_b); feat=[v1-v2, v1*v2];
//        out = tanh(feat@fc1^T + b1) @ fc2^T + b2
// B=512, W=128, K=337, OC=300. N split into 2 halves of 160 cols.

#define OC     300
#define KD     337
#define NBAT   512
#define NWRD   128
#define NKT    11
#define NSTRIP 10                 // 16-col strips per half
#define NGR    (NKT * NSTRIP * 64)  // 7040 granules (16B) per half

typedef _Float16 f16x8 __attribute__((ext_vector_type(8)));
typedef float    f32x4 __attribute__((ext_vector_type(4)));

#define GL_LDS(gp, lp, SZ)                                                        \
  __builtin_amdgcn_global_load_lds(                                               \
      (const __attribute__((address_space(1))) uint32_t*)(gp),                    \
      (__attribute__((address_space(3))) uint32_t*)(lp), SZ, 0, 0)

// Fragment-contiguous weights: granule g = ((nh*NKT + kt)*NSTRIP + strip)*64 + lane
// holds 8 f16: col o = nh*160 + strip*16 + (lane&15), k = kt*32 + (lane>>4)*8 + e.
// Zero-padded for o>=300 or k>=337 (kills A-garbage in tail).
__global__ void prep_wf_kernel(const float* __restrict__ cw, __half* __restrict__ Wf) {
  int g = blockIdx.x * 256 + threadIdx.x;
  if (g >= 2 * NGR) return;
  int lane  = g & 63;
  int t     = g >> 6;
  int strip = t % NSTRIP;
  int hk    = t / NSTRIP;
  int kt    = hk % NKT;
  int nh    = hk / NKT;
  int o     = nh * 160 + strip * 16 + (lane & 15);
  int kb    = kt * 32 + (lane >> 4) * 8;
  __half h8[8];
  #pragma unroll
  for (int e = 0; e < 8; ++e) {
    int k = kb + e;
    float v = (o < OC && k < KD) ? cw[o * KD + k] : 0.f;
    h8[e] = __float2half(v);
  }
  *reinterpret_cast<uint4*>(Wf + (size_t)g * 8) = *reinterpret_cast<const uint4*>(h8);
}

__global__ void prep_fc1t_kernel(const float* __restrict__ w, float* __restrict__ T) {
  int i = blockIdx.x * 256 + threadIdx.x;
  if (i >= 300 * 600) return;
  int j = i / 600, k = i - j * 600;
  T[k * 300 + j] = w[i];
}

// 2048 blocks = (item, col-half), 512 thr = 8 waves (4M x 2N).
// B persistent in LDS (loaded once). A direct global->reg, ping-pong,
// prefetch distance 2. NO barriers / vmcnt drains in the k-loop.
__global__ __launch_bounds__(512, 2) void encode_gemm(
    const float* __restrict__ x1, const float* __restrict__ x2,
    const __half* __restrict__ Wf, const float* __restrict__ cb,
    float* __restrict__ V)
{
  __shared__ uint4 Blds[NGR];        // 112,640 B (persistent)
  __shared__ float colmax[4][160];   //   2,560 B

  const int tid  = threadIdx.x;
  const int lane = tid & 63;
  const int wid  = tid >> 6;
  const int wm   = wid >> 1;   // 0..3 -> rows wm*32..+31
  const int wn   = wid & 1;    // 0..1 -> cols wn*80..+79 (within half)

  // chunked XCD swizzle (2048 % 8 == 0, bijective): an item's two halves
  // land on the same XCD -> second x read hits L2.
  const int logical = ((blockIdx.x & 7) << 8) | (blockIdx.x >> 3);
  const int item = logical >> 1;
  const int nh   = logical & 1;

  const float* xb = (item < NBAT ? x1 : x2) + (size_t)(item & (NBAT - 1)) * (NWRD * KD);

  // ---- B preload (once): 112,640 B via 14 dwordx4 DMA chunks ----
  const __half* wsrc = Wf + (size_t)nh * NGR * 8;
  #pragma unroll
  for (int j = 0; j < 13; ++j)
    GL_LDS(wsrc + (size_t)(j * 512 + tid) * 8, &Blds[j * 512 + tid], 16);
  if (tid < 384)
    GL_LDS(wsrc + (size_t)(13 * 512 + tid) * 8, &Blds[13 * 512 + tid], 16);

  // ---- A addressing (per-lane fragment rows) ----
  const int r0   = wm * 32 + (lane & 15);
  const float* rp0 = xb + (size_t)r0 * KD;         // mi = 0
  const float* rp1 = rp0 + 16 * KD;                // mi = 1
  const int h4   = lane >> 4;
  const int koct = h4 * 8;

  f32x4 P0lo0, P0hi0, P0lo1, P0hi1;   // ping buffer (2 rows x 8 f32)
  f32x4 P1lo0, P1hi0, P1lo1, P1hi1;   // pong buffer

#define LOADA(KT, Alo0, Ahi0, Alo1, Ahi1) do {                        \
    const float* p0_ = rp0 + (KT) * 32 + koct;                        \
    const float* p1_ = rp1 + (KT) * 32 + koct;                        \
    __builtin_memcpy(&Alo0, p0_,     16);                             \
    __builtin_memcpy(&Ahi0, p0_ + 4, 16);                             \
    __builtin_memcpy(&Alo1, p1_,     16);                             \
    __builtin_memcpy(&Ahi1, p1_ + 4, 16);                             \
  } while (0)

  // kt=10 tail: k = 320 + koct + e. h4<2 fully valid (<=335); h4>=2 only
  // k=336 matters (B zero-padded past 337) -> splat x[336] (finite, in-bounds).
#define LOADTAIL(Alo0, Ahi0, Alo1, Ahi1) do {                         \
    if (h4 < 2) {                                                     \
      const float* p0_ = rp0 + 320 + koct;                            \
      const float* p1_ = rp1 + 320 + koct;                            \
      __builtin_memcpy(&Alo0, p0_,     16);                           \
      __builtin_memcpy(&Ahi0, p0_ + 4, 16);                           \
      __builtin_memcpy(&Alo1, p1_,     16);                           \
      __builtin_memcpy(&Ahi1, p1_ + 4, 16);                           \
    } else {                                                          \
      float s0_ = rp0[336], s1_ = rp1[336];                           \
      Alo0 = (f32x4){s0_, s0_, s0_, s0_}; Ahi0 = Alo0;                \
      Alo1 = (f32x4){s1_, s1_, s1_, s1_}; Ahi1 = Alo1;                \
    }                                                                 \
  } while (0)

#define CVT2(Alo0, Ahi0, Alo1, Ahi1) do {                             \
    a0[0] = (_Float16)Alo0[0]; a0[1] = (_Float16)Alo0[1];             \
    a0[2] = (_Float16)Alo0[2]; a0[3] = (_Float16)Alo0[3];             \
    a0[4] = (_Float16)Ahi0[0]; a0[5] = (_Float16)Ahi0[1];             \
    a0[6] = (_Float16)Ahi0[2]; a0[7] = (_Float16)Ahi0[3];             \
    a1[0] = (_Float16)Alo1[0]; a1[1] = (_Float16)Alo1[1];             \
    a1[2] = (_Float16)Alo1[2]; a1[3] = (_Float16)Alo1[3];             \
    a1[4] = (_Float16)Ahi1[0]; a1[5] = (_Float16)Ahi1[1];             \
    a1[6] = (_Float16)Ahi1[2]; a1[7] = (_Float16)Ahi1[3];             \
  } while (0)

#define MFMAKT(KT) do {                                               \
    _Pragma("unroll")                                                 \
    for (int ni = 0; ni < 5; ++ni) {                                  \
      f16x8 b_ = *reinterpret_cast<const f16x8*>(                     \
          &Blds[((KT) * NSTRIP + wn * 5 + ni) * 64 + lane]);          \
      acc[0][ni] = __builtin_amdgcn_mfma_f32_16x16x32_f16(a0, b_, acc[0][ni], 0, 0, 0); \
      acc[1][ni] = __builtin_amdgcn_mfma_f32_16x16x32_f16(a1, b_, acc[1][ni], 0, 0, 0); \
    }                                                                 \
  } while (0)

  f32x4 acc[2][5];
  #pragma unroll
  for (int mi = 0; mi < 2; ++mi)
    #pragma unroll
    for (int ni = 0; ni < 5; ++ni)
      acc[mi][ni] = (f32x4){0.f, 0.f, 0.f, 0.f};

  LOADA(0, P0lo0, P0hi0, P0lo1, P0hi1);
  LOADA(1, P1lo0, P1hi0, P1lo1, P1hi1);

  asm volatile("s_waitcnt vmcnt(0)" ::: "memory");   // B (and A0/A1) landed
  __syncthreads();

  f16x8 a0, a1;
  #pragma unroll
  for (int kt = 0; kt < 10; kt += 2) {
    // even step: consume P0(kt), refill P0 with kt+2
    CVT2(P0lo0, P0hi0, P0lo1, P0hi1);
    if (kt + 2 <= 9)       LOADA(kt + 2, P0lo0, P0hi0, P0lo1, P0hi1);
    else                   LOADTAIL(P0lo0, P0hi0, P0lo1, P0hi1);     // kt==8 -> kt+2==10
    MFMAKT(kt);
    // odd step: consume P1(kt+1), refill P1 with kt+3
    CVT2(P1lo0, P1hi0, P1lo1, P1hi1);
    if (kt + 3 <= 9)       LOADA(kt + 3, P1lo0, P1hi0, P1lo1, P1hi1);
    MFMAKT(kt + 1);
  }
  CVT2(P0lo0, P0hi0, P0lo1, P0hi1);   // kt = 10 (tail, staged at kt==8)
  MFMAKT(10);

  // ---- epilogue: max over 128 rows -> relu(max + bias) ----
  // C/D layout: col = lane&15, rows spread over (lane>>4, reg) [m89]
  #pragma unroll
  for (int ni = 0; ni < 5; ++ni) {
    float m = fmaxf(fmaxf(fmaxf(acc[0][ni][0], acc[0][ni][1]),
                          fmaxf(acc[0][ni][2], acc[0][ni][3])),
                    fmaxf(fmaxf(acc[1][ni][0], acc[1][ni][1]),
                          fmaxf(acc[1][ni][2], acc[1][ni][3])));
    m = fmaxf(m, __shfl_xor(m, 16));
    m = fmaxf(m, __shfl_xor(m, 32));
    if (lane < 16) colmax[wm][wn * 80 + ni * 16 + lane] = m;   // disjoint per wave
  }
  __syncthreads();
  if (tid < 160) {
    int col = nh * 160 + tid;
    if (col < OC) {
      float v = fmaxf(fmaxf(colmax[0][tid], colmax[1][tid]),
                      fmaxf(colmax[2][tid], colmax[3][tid]));
      V[(size_t)item * OC + col] = fmaxf(v + cb[col], 0.f);
    }
  }
#undef LOADA
#undef LOADTAIL
#undef CVT2
#undef MFMAKT
}

// 64 blocks x 320 thr, 8 batch items per block.
__global__ __launch_bounds__(320) void head_kernel(
    const float* __restrict__ V, const float* __restrict__ T,
    const float* __restrict__ fc1b, const float* __restrict__ fc2w,
    const float* __restrict__ fc2b, float* __restrict__ out)
{
  __shared__ float feat[8][600];
  __shared__ float partial[8][5];
  const int tid  = threadIdx.x;
  const int lane = tid & 63;
  const int wid  = tid >> 6;
  const int b0   = blockIdx.x * 8;

  for (int idx = tid; idx < 8 * 600; idx += 320) {
    int q = idx / 600, k = idx - q * 600;
    int b = b0 + q;
    int c = (k < 300) ? k : k - 300;
    float a1 = V[(size_t)b * OC + c];
    float a2 = V[(size_t)(NBAT + b) * OC + c];
    feat[q][k] = (k < 300) ? (a1 - a2) : (a1 * a2);
  }
  __syncthreads();

  const int j = tid;
  float h[8] = {0.f, 0.f, 0.f, 0.f, 0.f, 0.f, 0.f, 0.f};
  if (j < 300) {
    for (int k4 = 0; k4 < 150; ++k4) {
      float w0 = T[(k4 * 4 + 0) * 300 + j];
      float w1 = T[(k4 * 4 + 1) * 300 + j];
      float w2 = T[(k4 * 4 + 2) * 300 + j];
      float w3 = T[(k4 * 4 + 3) * 300 + j];
      #pragma unroll
      for (int q = 0; q < 8; ++q) {
        float4 fv = *reinterpret_cast<const float4*>(&feat[q][k4 * 4]);
        h[q] = fmaf(fv.x, w0, h[q]);
        h[q] = fmaf(fv.y, w1, h[q]);
        h[q] = fmaf(fv.z, w2, h[q]);
        h[q] = fmaf(fv.w, w3, h[q]);
      }
    }
  }
  float bias = (j < 300) ? fc1b[j] : 0.f;
  float w2j  = (j < 300) ? fc2w[j] : 0.f;
  #pragma unroll
  for (int q = 0; q < 8; ++q) {
    float g = (j < 300) ? tanhf(h[q] + bias) * w2j : 0.f;
    #pragma unroll
    for (int s = 1; s < 64; s <<= 1) g += __shfl_xor(g, s);
    if (lane == 0) partial[q][wid] = g;
  }
  __syncthreads();
  if (tid < 8) {
    float s = fc2b[0];
    #pragma unroll
    for (int wv = 0; wv < 5; ++wv) s += partial[tid][wv];
    out[b0 + tid] = s;
  }
}

extern "C" void kernel_launch(void* const* d_in, const int* in_sizes, int n_in,
                              void* d_out, int out_size, void* d_ws, size_t ws_size,
                              hipStream_t stream) {
  const float* x1     = (const float*)d_in[0];
  const float* x2     = (const float*)d_in[1];
  const float* conv_w = (const float*)d_in[2];
  const float* conv_b = (const float*)d_in[3];
  const float* fc1_w  = (const float*)d_in[4];
  const float* fc1_b  = (const float*)d_in[5];
  const float* fc2_w  = (const float*)d_in[6];
  const float* fc2_b  = (const float*)d_in[7];
  float* out = (float*)d_out;

  uint8_t* ws = (uint8_t*)d_ws;
  __half* Wf = (__half*)ws;                                // 2*7040*16 = 225,280 B
  float*  V  = (float*)(ws + 225280);                      // 1024*300*4 = 1,228,800 B
  float*  T  = (float*)(ws + 225280 + 1228800);            // 600*300*4  = 720,000 B

  prep_wf_kernel<<<(2 * NGR + 255) / 256, 256, 0, stream>>>(conv_w, Wf);
  prep_fc1t_kernel<<<(300 * 600 + 255) / 256, 256, 0, stream>>>(fc1_w, T);
  encode_gemm<<<2048, 512, 0, stream>>>(x1, x2, Wf, conv_b, V);
  head_kernel<<<64, 320, 0, stream>>>(V, T, fc1_b, fc2_w, fc2_b, out);
}